// Round 7
// baseline (2556.168 us; speedup 1.0000x reference)
//
#include <hip/hip_runtime.h>
#include <hip/hip_bf16.h>
#include <math.h>

// Problem constants
#define B   64
#define C   1024
#define HH  16
#define DD  64
#define MM  2048
#define LL  2049   // M+1
#define SCALE 0.125f
#define NCHC 9     // ctx row chunks
#define CHC  228   // rows per ctx chunk (9*228 = 2052 >= 2049)
#define LT6ROWS 256 // logits rows per block-tile

// ---------------- generic split-K GEMM: out_partial[kc][64][1024] ----------------
__global__ __launch_bounds__(256) void k_gemm(
    const float* __restrict__ A, int a_row_stride, int a_bx_off,
    const float* __restrict__ W, float* __restrict__ P) {
  __shared__ __attribute__((aligned(16))) float a_s[64 * 132];
  __shared__ __attribute__((aligned(16))) float b_s[128 * 68];
  int t = threadIdx.x;
  int jt = blockIdx.x, kc = blockIdx.y;
  const float* Ab = A + (size_t)jt * a_bx_off;
  int k0 = kc * 128;
  for (int idx = t; idx < 2048; idx += 256) {
    int bb = idx >> 5, f4 = idx & 31;
    float4 v = *(const float4*)&Ab[(size_t)bb * a_row_stride + k0 + 4 * f4];
    *(float4*)&a_s[bb * 132 + 4 * f4] = v;
  }
  for (int idx = t; idx < 2048; idx += 256) {
    int kk = idx >> 4, f4 = idx & 15;
    float4 v = *(const float4*)&W[(size_t)(k0 + kk) * 1024 + jt * 64 + 4 * f4];
    *(float4*)&b_s[kk * 68 + 4 * f4] = v;
  }
  __syncthreads();
  int j0 = (t & 15) * 4, b0 = (t >> 4) * 4;
  float4 acc[4];
#pragma unroll
  for (int i = 0; i < 4; ++i) acc[i] = make_float4(0.f, 0.f, 0.f, 0.f);
  for (int k = 0; k < 128; k += 4) {
    float4 w0 = *(const float4*)&b_s[(k + 0) * 68 + j0];
    float4 w1 = *(const float4*)&b_s[(k + 1) * 68 + j0];
    float4 w2 = *(const float4*)&b_s[(k + 2) * 68 + j0];
    float4 w3 = *(const float4*)&b_s[(k + 3) * 68 + j0];
#pragma unroll
    for (int i = 0; i < 4; ++i) {
      float4 av = *(const float4*)&a_s[(b0 + i) * 132 + k];
      acc[i].x += av.x * w0.x + av.y * w1.x + av.z * w2.x + av.w * w3.x;
      acc[i].y += av.x * w0.y + av.y * w1.y + av.z * w2.y + av.w * w3.y;
      acc[i].z += av.x * w0.z + av.y * w1.z + av.z * w2.z + av.w * w3.z;
      acc[i].w += av.x * w0.w + av.y * w1.w + av.z * w2.w + av.w * w3.w;
    }
  }
  size_t ob = (size_t)kc * 65536 + jt * 64;
#pragma unroll
  for (int i = 0; i < 4; ++i)
    *(float4*)&P[ob + (size_t)(b0 + i) * 1024 + j0] = acc[i];
}

__global__ __launch_bounds__(256) void k_reduce_qp(
    const float* __restrict__ P, const float* __restrict__ bq,
    const float* __restrict__ u, const float* __restrict__ v,
    float* __restrict__ qu, float* __restrict__ qv) {
  int idx = blockIdx.x * 256 + threadIdx.x;
  int b = idx >> 8, f4 = idx & 255;
  size_t off = (size_t)b * 1024 + 4 * f4;
  float4 s = *(const float4*)&P[off];
#pragma unroll
  for (int kc = 1; kc < 8; ++kc) {
    float4 t4 = *(const float4*)&P[(size_t)kc * 65536 + off];
    s.x += t4.x; s.y += t4.y; s.z += t4.z; s.w += t4.w;
  }
  float4 bb = *(const float4*)&bq[4 * f4];
  s.x += bb.x; s.y += bb.y; s.z += bb.z; s.w += bb.w;
  float4 uu = *(const float4*)&u[4 * f4];
  float4 vv = *(const float4*)&v[4 * f4];
  float4 o1 = make_float4(s.x + uu.x, s.y + uu.y, s.z + uu.z, s.w + uu.w);
  float4 o2 = make_float4(s.x + vv.x, s.y + vv.y, s.z + vv.z, s.w + vv.w);
  *(float4*)&qu[off] = o1;
  *(float4*)&qv[off] = o2;
}

__global__ __launch_bounds__(256) void k_reduce1(
    const float* __restrict__ P, const float* __restrict__ bias,
    float* __restrict__ out) {
  int idx = blockIdx.x * 256 + threadIdx.x;
  int b = idx >> 8, f4 = idx & 255;
  size_t off = (size_t)b * 1024 + 4 * f4;
  float4 s = *(const float4*)&P[off];
#pragma unroll
  for (int kc = 1; kc < 8; ++kc) {
    float4 t4 = *(const float4*)&P[(size_t)kc * 65536 + off];
    s.x += t4.x; s.y += t4.y; s.z += t4.z; s.w += t4.w;
  }
  float4 bb = *(const float4*)&bias[4 * f4];
  s.x += bb.x; s.y += bb.y; s.z += bb.z; s.w += bb.w;
  *(float4*)&out[off] = s;
}

// ---------------- wtilde: per-h GEMM ----------------
__global__ __launch_bounds__(256) void k_wtilde(
    const float* __restrict__ qu, const float* __restrict__ Wk,
    float* __restrict__ wt) {
  __shared__ __attribute__((aligned(16))) float a_s[64 * 68];
  __shared__ __attribute__((aligned(16))) float w_s[64 * 68];
  int t = threadIdx.x, ct = blockIdx.x, h = blockIdx.y;
  for (int idx = t; idx < 1024; idx += 256) {
    int bb = idx >> 4, f4 = idx & 15;
    *(float4*)&a_s[bb * 68 + 4 * f4] =
        *(const float4*)&qu[(size_t)bb * 1024 + h * 64 + 4 * f4];
  }
  for (int idx = t; idx < 1024; idx += 256) {
    int cc = idx >> 4, f4 = idx & 15;
    *(float4*)&w_s[cc * 68 + 4 * f4] =
        *(const float4*)&Wk[(size_t)(ct * 64 + cc) * 1024 + h * 64 + 4 * f4];
  }
  __syncthreads();
  int c0 = (t & 15) * 4, b0 = (t >> 4) * 4;
  float acc[4][4] = {};
  for (int d = 0; d < 64; d += 4) {
    float4 w0 = *(const float4*)&w_s[(c0 + 0) * 68 + d];
    float4 w1 = *(const float4*)&w_s[(c0 + 1) * 68 + d];
    float4 w2 = *(const float4*)&w_s[(c0 + 2) * 68 + d];
    float4 w3 = *(const float4*)&w_s[(c0 + 3) * 68 + d];
#pragma unroll
    for (int i = 0; i < 4; ++i) {
      float4 av = *(const float4*)&a_s[(b0 + i) * 68 + d];
      acc[i][0] += av.x * w0.x + av.y * w0.y + av.z * w0.z + av.w * w0.w;
      acc[i][1] += av.x * w1.x + av.y * w1.y + av.z * w1.z + av.w * w1.w;
      acc[i][2] += av.x * w2.x + av.y * w2.y + av.z * w2.z + av.w * w2.w;
      acc[i][3] += av.x * w3.x + av.y * w3.y + av.z * w3.z + av.w * w3.w;
    }
  }
#pragma unroll
  for (int i = 0; i < 4; ++i) {
    float4 o = make_float4(acc[i][0], acc[i][1], acc[i][2], acc[i][3]);
    *(float4*)&wt[(size_t)((b0 + i) * 16 + h) * 1024 + ct * 64 + c0] = o;
  }
}

// ---------------- sinusoidal table, reversed ----------------
__global__ void k_rtab(float* __restrict__ rtab) {
  int idx = blockIdx.x * 256 + threadIdx.x;
  if (idx >= LL * 64) return;
  int l = idx >> 6, d = idx & 63;
  float p = (float)(LL - 1 - l);
  int dd = d & 31;
  float f = 1.0f / powf(10000.0f, (float)dd * (1.0f / 32.0f));
  float a = p * f;
  rtab[idx] = (d < 32) ? sinf(a) : cosf(a);
}

// ---------------- bd[b,h,l] = sum_d qv[b,h,d]*rtab[l,d] ----------------
// grid (17, 64): 128 l-rows per block
__global__ __launch_bounds__(256) void k_bd(
    const float* __restrict__ qv, const float* __restrict__ rtab,
    float* __restrict__ bd) {
  __shared__ __attribute__((aligned(16))) float rt_s[128 * 68];
  int t = threadIdx.x, ch = blockIdx.x, b = blockIdx.y;
  int l0 = ch * 128;
  int nrows = min(128, LL - l0);
  for (int idx = t; idx < nrows * 16; idx += 256) {
    int r = idx >> 4, d4 = idx & 15;
    *(float4*)&rt_s[r * 68 + 4 * d4] =
        *(const float4*)&rtab[(size_t)(l0 + r) * 64 + 4 * d4];
  }
  __syncthreads();
  for (int idx = t; idx < 16 * 128; idx += 256) {
    int h = idx >> 7, r = idx & 127;
    if (r < nrows) {
      const float* qh = &qv[(size_t)b * 1024 + h * 64];
      const float* rr = &rt_s[r * 68];
      float s = 0.f;
#pragma unroll
      for (int d4 = 0; d4 < 16; ++d4) {
        float4 rv = *(const float4*)&rr[4 * d4];
        float4 qq = *(const float4*)&qh[4 * d4];
        s += rv.x * qq.x + rv.y * qq.y + rv.z * qq.z + rv.w * qq.w;
      }
      bd[(size_t)(b * 16 + h) * LL + l0 + r] = s;
    }
  }
}

// ---------------- logits: tiled GEMM [256 l x 1024 c] x [1024 c x 16 h] ----------
// grid (9, 64). Thread (tr=t&63, tc=t>>6): rows {tr+64r}, h {4tc+hh}.
// cat in LDS with XOR-swizzled float4 slots (rows strided 64 -> 8 distinct
// keys per read instr -> b128 at the 8-phase minimum). wt in LDS, read
// wave-uniform (broadcast). No VMEM in the k-loop, no cross-lane reduce.
__global__ __launch_bounds__(256, 4) void k_logits6(
    const float* __restrict__ x, const float* __restrict__ mem,
    const float* __restrict__ wt, float* __restrict__ logits) {
  __shared__ __attribute__((aligned(16))) float cat_s[LT6ROWS * 32];
  __shared__ __attribute__((aligned(16))) float wt_s[16 * 33];
  int t = threadIdx.x;
  int b = blockIdx.y, tile = blockIdx.x;
  int l0 = tile * LT6ROWS;
  int tr = t & 63, tc = t >> 6;
  const float* wtb = &wt[(size_t)b * 16384];
  float acc[4][4] = {};  // [r][hh]

  for (int c0 = 0; c0 < 1024; c0 += 32) {
    // stage cat: 256 rows x 32 floats, coalesced 128B/row, swizzled slots
#pragma unroll
    for (int i = 0; i < 8; ++i) {
      int idx = i * 256 + t;
      int r = idx >> 3, c4 = idx & 7;
      int l = min(l0 + r, LL - 1);
      const float* src = (l < MM) ? &mem[((size_t)b * MM + l) * 1024]
                                  : &x[(size_t)b * 1024];
      float4 v = *(const float4*)&src[c0 + 4 * c4];
      *(float4*)&cat_s[r * 32 + 4 * (c4 ^ (r & 7))] = v;
    }
    // stage wt: 16 h x 32 floats
    if (t < 128) {
      int h = t >> 3, c4 = t & 7;
      *(float4*)&wt_s[h * 33 + 4 * c4] =
          *(const float4*)&wtb[h * 1024 + c0 + 4 * c4];
    }
    __syncthreads();
#pragma unroll
    for (int k4 = 0; k4 < 8; ++k4) {
      float4 wv0 = *(const float4*)&wt_s[(tc * 4 + 0) * 33 + 4 * k4];
      float4 wv1 = *(const float4*)&wt_s[(tc * 4 + 1) * 33 + 4 * k4];
      float4 wv2 = *(const float4*)&wt_s[(tc * 4 + 2) * 33 + 4 * k4];
      float4 wv3 = *(const float4*)&wt_s[(tc * 4 + 3) * 33 + 4 * k4];
#pragma unroll
      for (int r = 0; r < 4; ++r) {
        float4 cv = *(const float4*)&cat_s[(tr + 64 * r) * 32 +
                                           4 * (k4 ^ (tr & 7))];
        acc[r][0] += cv.x * wv0.x + cv.y * wv0.y + cv.z * wv0.z + cv.w * wv0.w;
        acc[r][1] += cv.x * wv1.x + cv.y * wv1.y + cv.z * wv1.z + cv.w * wv1.w;
        acc[r][2] += cv.x * wv2.x + cv.y * wv2.y + cv.z * wv2.z + cv.w * wv2.w;
        acc[r][3] += cv.x * wv3.x + cv.y * wv3.y + cv.z * wv3.z + cv.w * wv3.w;
      }
    }
    __syncthreads();
  }
#pragma unroll
  for (int r = 0; r < 4; ++r) {
    int myl = l0 + tr + 64 * r;
    if (myl < LL) {
#pragma unroll
      for (int hh = 0; hh < 4; ++hh) {
        int h = tc * 4 + hh;
        logits[(size_t)(b * 16 + h) * LL + myl] = acc[r][hh];
      }
    }
  }
}

// ---------------- softmax over l: reads (ac + bd)*scale, writes attn in place ----
__global__ __launch_bounds__(256) void k_softmax(float* __restrict__ logits,
                                                 const float* __restrict__ bd) {
  __shared__ float red[8];
  int t = threadIdx.x;
  size_t base = (size_t)blockIdx.x * LL;
  float rv[9];
  float m = -1e30f;
#pragma unroll
  for (int k = 0; k < 9; ++k) {
    int i = t + k * 256;
    rv[k] = (i < LL) ? (logits[base + i] + bd[base + i]) * SCALE : -1e30f;
    m = fmaxf(m, rv[k]);
  }
#pragma unroll
  for (int s = 1; s < 64; s <<= 1) m = fmaxf(m, __shfl_xor(m, s, 64));
  if ((t & 63) == 0) red[t >> 6] = m;
  __syncthreads();
  m = fmaxf(fmaxf(red[0], red[1]), fmaxf(red[2], red[3]));
  float sum = 0.f;
#pragma unroll
  for (int k = 0; k < 9; ++k) {
    int i = t + k * 256;
    float e = __expf(rv[k] - m);
    rv[k] = e;
    if (i < LL) sum += e;
  }
#pragma unroll
  for (int s = 1; s < 64; s <<= 1) sum += __shfl_xor(sum, s, 64);
  if ((t & 63) == 0) red[4 + (t >> 6)] = sum;
  __syncthreads();
  float inv = 1.0f / (red[4] + red[5] + red[6] + red[7]);
#pragma unroll
  for (int k = 0; k < 9; ++k) {
    int i = t + k * 256;
    if (i < LL) logits[base + i] = rv[k] * inv;
  }
}

// ---------------- ctx pass: register-resident, global-direct ----------------
__global__ __launch_bounds__(256) void k_ctx(
    const float* __restrict__ x, const float* __restrict__ mem,
    const float* __restrict__ attn, float* __restrict__ part) {
  __shared__ __attribute__((aligned(16))) float att_s[CHC * 20];
  int t = threadIdx.x;
  int lane = t & 63, w = t >> 6;
  int b = blockIdx.y;
  int ch = blockIdx.x >> 2, cq = blockIdx.x & 3;
  int l0 = ch * CHC, lend = min(LL, l0 + CHC);
  int natt = lend - l0;
  int c_off = cq * 256 + lane * 4;
#pragma unroll
  for (int h = 0; h < 16; ++h)
    for (int r = t; r < natt; r += 256)
      att_s[r * 20 + h] = attn[(size_t)(b * 16 + h) * LL + l0 + r];
  __syncthreads();
  float4 acc[16];
#pragma unroll
  for (int i = 0; i < 16; ++i) acc[i] = make_float4(0.f, 0.f, 0.f, 0.f);
  const float* xrow = &x[(size_t)b * 1024 + c_off];
  const float* memb = &mem[(size_t)b * MM * 1024 + c_off];

  for (int g0 = l0 + w * 8; g0 < lend; g0 += 32) {
    int nr = min(8, lend - g0);
    float4 rb[8];
#pragma unroll
    for (int r = 0; r < 8; ++r) {
      int l = g0 + r;
      rb[r] = *(const float4*)((l < MM) ? &memb[(size_t)l * 1024] : xrow);
    }
#pragma unroll
    for (int r = 0; r < 8; ++r) {
      if (r < nr) {
        int ri = g0 + r - l0;
        const float4* a4 = (const float4*)&att_s[ri * 20];
        float4 aA = a4[0], aB = a4[1], aC = a4[2], aD = a4[3];
        float4 rv = rb[r];
#define ACC1(i, s)                                                       \
  acc[i].x += (s) * rv.x; acc[i].y += (s) * rv.y;                        \
  acc[i].z += (s) * rv.z; acc[i].w += (s) * rv.w;
        ACC1(0, aA.x) ACC1(1, aA.y) ACC1(2, aA.z) ACC1(3, aA.w)
        ACC1(4, aB.x) ACC1(5, aB.y) ACC1(6, aB.z) ACC1(7, aB.w)
        ACC1(8, aC.x) ACC1(9, aC.y) ACC1(10, aC.z) ACC1(11, aC.w)
        ACC1(12, aD.x) ACC1(13, aD.y) ACC1(14, aD.z) ACC1(15, aD.w)
#undef ACC1
      }
    }
  }
  __syncthreads();
  float* accb = att_s;
  for (int ww = 0; ww < 4; ++ww) {
    if (w == ww) {
      if (ww == 0) {
#pragma unroll
        for (int h = 0; h < 16; ++h)
          *(float4*)&accb[h * 256 + lane * 4] = acc[h];
      } else {
#pragma unroll
        for (int h = 0; h < 16; ++h) {
          float4 vv = *(const float4*)&accb[h * 256 + lane * 4];
          vv.x += acc[h].x; vv.y += acc[h].y;
          vv.z += acc[h].z; vv.w += acc[h].w;
          *(float4*)&accb[h * 256 + lane * 4] = vv;
        }
      }
    }
    __syncthreads();
  }
  size_t pb = (size_t)((b * NCHC + ch) * 16) * 1024 + cq * 256;
  for (int idx = t; idx < 1024; idx += 256) {
    int h = idx >> 6, c4 = idx & 63;
    *(float4*)&part[pb + (size_t)h * 1024 + 4 * c4] =
        *(const float4*)&accb[h * 256 + 4 * c4];
  }
}

// ---------------- sum 9 chunk partials -> ctx ----------------
__global__ __launch_bounds__(256) void k_ctxreduce(
    const float* __restrict__ part, float* __restrict__ ctx) {
  int o4 = blockIdx.x * 256 + threadIdx.x;
  size_t o = (size_t)o4 * 4;
  int b = (int)(o >> 14);
  int rem = (int)(o & 16383);
  const float* p = &part[(size_t)b * (NCHC * 16384) + rem];
  float4 s = *(const float4*)p;
#pragma unroll
  for (int chk = 1; chk < NCHC; ++chk) {
    float4 v = *(const float4*)&p[(size_t)chk * 16384];
    s.x += v.x; s.y += v.y; s.z += v.z; s.w += v.w;
  }
  *(float4*)&ctx[o] = s;
}

extern "C" void kernel_launch(void* const* d_in, const int* in_sizes, int n_in,
                              void* d_out, int out_size, void* d_ws,
                              size_t ws_size, hipStream_t stream) {
  const float* x = (const float*)d_in[0];
  const float* mem = (const float*)d_in[1];
  const float* Wq = (const float*)d_in[2];
  const float* bq = (const float*)d_in[3];
  const float* Wk = (const float*)d_in[4];
  // d_in[5] = bk : constant over l -> cancels in softmax, unused.
  const float* Wv = (const float*)d_in[6];
  const float* bv = (const float*)d_in[7];
  const float* u_bias = (const float*)d_in[8];
  const float* v_bias = (const float*)d_in[9];
  const float* Wo = (const float*)d_in[10];
  const float* bo = (const float*)d_in[11];
  float* out = (float*)d_out;

  float* ws = (float*)d_ws;
  // Region A (persistent): 3,343,360 floats
  float* qu = ws;                         // 65536
  float* qv = qu + 65536;                 // 65536
  float* logits = qv + 65536;             // 2098176
  float* ctx = logits + 2098176;          // 1048576
  float* out1 = ctx + 1048576;            // 65536
  // Region B (aliased): 9,437,184 floats (= part)
  float* Bb = out1 + 65536;
  float* P = Bb;                          // 524288
  float* wt = Bb + 524288;                // 1048576 (dead after k_logits6)
  float* rtab = Bb + 524288 + 1048576;    // 131200  (dead after k_bd)
  float* bd = Bb + 524288 + 1048576 + 131200;  // 2098176 (dead after k_softmax)
  float* part = Bb;                       // 9437184 (k_ctx..k_ctxreduce only)
  // total = 12,780,544 floats = 51.1 MB

  k_gemm<<<dim3(16, 8), 256, 0, stream>>>(x, 1024, 0, Wq, P);
  k_rtab<<<dim3(513), 256, 0, stream>>>(rtab);
  k_reduce_qp<<<dim3(64), 256, 0, stream>>>(P, bq, u_bias, v_bias, qu, qv);
  k_wtilde<<<dim3(16, 16), 256, 0, stream>>>(qu, Wk, wt);
  k_bd<<<dim3(17, 64), 256, 0, stream>>>(qv, rtab, bd);
  k_logits6<<<dim3(9, 64), 256, 0, stream>>>(x, mem, wt, logits);
  k_softmax<<<dim3(1024), 256, 0, stream>>>(logits, bd);
  k_ctx<<<dim3(36, 64), 256, 0, stream>>>(x, mem, logits, part);
  k_ctxreduce<<<dim3(1024), 256, 0, stream>>>(part, ctx);
  k_gemm<<<dim3(16, 8), 256, 0, stream>>>(ctx, 16384, 1024, Wv, P);
  k_reduce1<<<dim3(64), 256, 0, stream>>>(P, bv, out1);
  k_gemm<<<dim3(16, 8), 256, 0, stream>>>(out1, 1024, 0, Wo, P);
  k_reduce1<<<dim3(64), 256, 0, stream>>>(P, bo, out);
}

// Round 8
// 657.135 us; speedup vs baseline: 3.8899x; 3.8899x over previous
//
#include <hip/hip_runtime.h>
#include <hip/hip_bf16.h>
#include <math.h>

// Problem constants
#define B   64
#define C   1024
#define HH  16
#define DD  64
#define MM  2048
#define LL  2049   // M+1
#define SCALE 0.125f
#define NCHC 9     // ctx row chunks
#define CHC  228   // rows per ctx chunk (9*228 = 2052 >= 2049)

// ---------------- generic split-K GEMM: out_partial[kc][64][1024] ----------------
__global__ __launch_bounds__(256) void k_gemm(
    const float* __restrict__ A, int a_row_stride, int a_bx_off,
    const float* __restrict__ W, float* __restrict__ P) {
  __shared__ __attribute__((aligned(16))) float a_s[64 * 132];
  __shared__ __attribute__((aligned(16))) float b_s[128 * 68];
  int t = threadIdx.x;
  int jt = blockIdx.x, kc = blockIdx.y;
  const float* Ab = A + (size_t)jt * a_bx_off;
  int k0 = kc * 128;
  for (int idx = t; idx < 2048; idx += 256) {
    int bb = idx >> 5, f4 = idx & 31;
    float4 v = *(const float4*)&Ab[(size_t)bb * a_row_stride + k0 + 4 * f4];
    *(float4*)&a_s[bb * 132 + 4 * f4] = v;
  }
  for (int idx = t; idx < 2048; idx += 256) {
    int kk = idx >> 4, f4 = idx & 15;
    float4 v = *(const float4*)&W[(size_t)(k0 + kk) * 1024 + jt * 64 + 4 * f4];
    *(float4*)&b_s[kk * 68 + 4 * f4] = v;
  }
  __syncthreads();
  int j0 = (t & 15) * 4, b0 = (t >> 4) * 4;
  float4 acc[4];
#pragma unroll
  for (int i = 0; i < 4; ++i) acc[i] = make_float4(0.f, 0.f, 0.f, 0.f);
  for (int k = 0; k < 128; k += 4) {
    float4 w0 = *(const float4*)&b_s[(k + 0) * 68 + j0];
    float4 w1 = *(const float4*)&b_s[(k + 1) * 68 + j0];
    float4 w2 = *(const float4*)&b_s[(k + 2) * 68 + j0];
    float4 w3 = *(const float4*)&b_s[(k + 3) * 68 + j0];
#pragma unroll
    for (int i = 0; i < 4; ++i) {
      float4 av = *(const float4*)&a_s[(b0 + i) * 132 + k];
      acc[i].x += av.x * w0.x + av.y * w1.x + av.z * w2.x + av.w * w3.x;
      acc[i].y += av.x * w0.y + av.y * w1.y + av.z * w2.y + av.w * w3.y;
      acc[i].z += av.x * w0.z + av.y * w1.z + av.z * w2.z + av.w * w3.z;
      acc[i].w += av.x * w0.w + av.y * w1.w + av.z * w2.w + av.w * w3.w;
    }
  }
  size_t ob = (size_t)kc * 65536 + jt * 64;
#pragma unroll
  for (int i = 0; i < 4; ++i)
    *(float4*)&P[ob + (size_t)(b0 + i) * 1024 + j0] = acc[i];
}

__global__ __launch_bounds__(256) void k_reduce_qp(
    const float* __restrict__ P, const float* __restrict__ bq,
    const float* __restrict__ u, const float* __restrict__ v,
    float* __restrict__ qu, float* __restrict__ qv) {
  int idx = blockIdx.x * 256 + threadIdx.x;
  int b = idx >> 8, f4 = idx & 255;
  size_t off = (size_t)b * 1024 + 4 * f4;
  float4 s = *(const float4*)&P[off];
#pragma unroll
  for (int kc = 1; kc < 8; ++kc) {
    float4 t4 = *(const float4*)&P[(size_t)kc * 65536 + off];
    s.x += t4.x; s.y += t4.y; s.z += t4.z; s.w += t4.w;
  }
  float4 bb = *(const float4*)&bq[4 * f4];
  s.x += bb.x; s.y += bb.y; s.z += bb.z; s.w += bb.w;
  float4 uu = *(const float4*)&u[4 * f4];
  float4 vv = *(const float4*)&v[4 * f4];
  float4 o1 = make_float4(s.x + uu.x, s.y + uu.y, s.z + uu.z, s.w + uu.w);
  float4 o2 = make_float4(s.x + vv.x, s.y + vv.y, s.z + vv.z, s.w + vv.w);
  *(float4*)&qu[off] = o1;
  *(float4*)&qv[off] = o2;
}

__global__ __launch_bounds__(256) void k_reduce1(
    const float* __restrict__ P, const float* __restrict__ bias,
    float* __restrict__ out) {
  int idx = blockIdx.x * 256 + threadIdx.x;
  int b = idx >> 8, f4 = idx & 255;
  size_t off = (size_t)b * 1024 + 4 * f4;
  float4 s = *(const float4*)&P[off];
#pragma unroll
  for (int kc = 1; kc < 8; ++kc) {
    float4 t4 = *(const float4*)&P[(size_t)kc * 65536 + off];
    s.x += t4.x; s.y += t4.y; s.z += t4.z; s.w += t4.w;
  }
  float4 bb = *(const float4*)&bias[4 * f4];
  s.x += bb.x; s.y += bb.y; s.z += bb.z; s.w += bb.w;
  *(float4*)&out[off] = s;
}

// ---------------- wtilde: per-h GEMM ----------------
__global__ __launch_bounds__(256) void k_wtilde(
    const float* __restrict__ qu, const float* __restrict__ Wk,
    float* __restrict__ wt) {
  __shared__ __attribute__((aligned(16))) float a_s[64 * 68];
  __shared__ __attribute__((aligned(16))) float w_s[64 * 68];
  int t = threadIdx.x, ct = blockIdx.x, h = blockIdx.y;
  for (int idx = t; idx < 1024; idx += 256) {
    int bb = idx >> 4, f4 = idx & 15;
    *(float4*)&a_s[bb * 68 + 4 * f4] =
        *(const float4*)&qu[(size_t)bb * 1024 + h * 64 + 4 * f4];
  }
  for (int idx = t; idx < 1024; idx += 256) {
    int cc = idx >> 4, f4 = idx & 15;
    *(float4*)&w_s[cc * 68 + 4 * f4] =
        *(const float4*)&Wk[(size_t)(ct * 64 + cc) * 1024 + h * 64 + 4 * f4];
  }
  __syncthreads();
  int c0 = (t & 15) * 4, b0 = (t >> 4) * 4;
  float acc[4][4] = {};
  for (int d = 0; d < 64; d += 4) {
    float4 w0 = *(const float4*)&w_s[(c0 + 0) * 68 + d];
    float4 w1 = *(const float4*)&w_s[(c0 + 1) * 68 + d];
    float4 w2 = *(const float4*)&w_s[(c0 + 2) * 68 + d];
    float4 w3 = *(const float4*)&w_s[(c0 + 3) * 68 + d];
#pragma unroll
    for (int i = 0; i < 4; ++i) {
      float4 av = *(const float4*)&a_s[(b0 + i) * 68 + d];
      acc[i][0] += av.x * w0.x + av.y * w0.y + av.z * w0.z + av.w * w0.w;
      acc[i][1] += av.x * w1.x + av.y * w1.y + av.z * w1.z + av.w * w1.w;
      acc[i][2] += av.x * w2.x + av.y * w2.y + av.z * w2.z + av.w * w2.w;
      acc[i][3] += av.x * w3.x + av.y * w3.y + av.z * w3.z + av.w * w3.w;
    }
  }
#pragma unroll
  for (int i = 0; i < 4; ++i) {
    float4 o = make_float4(acc[i][0], acc[i][1], acc[i][2], acc[i][3]);
    *(float4*)&wt[(size_t)((b0 + i) * 16 + h) * 1024 + ct * 64 + c0] = o;
  }
}

// ---------------- sinusoidal table, reversed ----------------
__global__ void k_rtab(float* __restrict__ rtab) {
  int idx = blockIdx.x * 256 + threadIdx.x;
  if (idx >= LL * 64) return;
  int l = idx >> 6, d = idx & 63;
  float p = (float)(LL - 1 - l);
  int dd = d & 31;
  float f = 1.0f / powf(10000.0f, (float)dd * (1.0f / 32.0f));
  float a = p * f;
  rtab[idx] = (d < 32) ? sinf(a) : cosf(a);
}

// ---------------- bd[b,h,l] = sum_d qv[b,h,d]*rtab[l,d] ----------------
// grid (17, 64): 128 l-rows per block
__global__ __launch_bounds__(256) void k_bd(
    const float* __restrict__ qv, const float* __restrict__ rtab,
    float* __restrict__ bd) {
  __shared__ __attribute__((aligned(16))) float rt_s[128 * 68];
  int t = threadIdx.x, ch = blockIdx.x, b = blockIdx.y;
  int l0 = ch * 128;
  int nrows = min(128, LL - l0);
  for (int idx = t; idx < nrows * 16; idx += 256) {
    int r = idx >> 4, d4 = idx & 15;
    *(float4*)&rt_s[r * 68 + 4 * d4] =
        *(const float4*)&rtab[(size_t)(l0 + r) * 64 + 4 * d4];
  }
  __syncthreads();
  for (int idx = t; idx < 16 * 128; idx += 256) {
    int h = idx >> 7, r = idx & 127;
    if (r < nrows) {
      const float* qh = &qv[(size_t)b * 1024 + h * 64];
      const float* rr = &rt_s[r * 68];
      float s = 0.f;
#pragma unroll
      for (int d4 = 0; d4 < 16; ++d4) {
        float4 rv = *(const float4*)&rr[4 * d4];
        float4 qq = *(const float4*)&qh[4 * d4];
        s += rv.x * qq.x + rv.y * qq.y + rv.z * qq.z + rv.w * qq.w;
      }
      bd[(size_t)(b * 16 + h) * LL + l0 + r] = s;
    }
  }
}

// ---------------- logits: register-only, contiguous loads, one butterfly ----------
// grid (129, 64). Wave owns 4 rows; lane = (cg=lane&15, hl=lane>>4).
// c-chunk q of 256: wt chunk in regs wr[j][jh] (64 VGPR, reloaded per q);
// cat loads: float4 at (4q+j)*64 + cg*4 -> 256B aligned contiguous per instr
// (4-way hl duplication merges in the coalescer). p[4r][4jh] persists.
// End: 15-shuffle packed butterfly over cg bits -> 64 lanes hold the 64
// (row,h) results -> single guarded store.
__global__ __launch_bounds__(256) void k_logits7(
    const float* __restrict__ x, const float* __restrict__ mem,
    const float* __restrict__ wt, float* __restrict__ logits) {
  int t = threadIdx.x;
  int lane = t & 63, w = t >> 6;
  int cg = lane & 15, hl = lane >> 4;
  int b = blockIdx.y, ch = blockIdx.x;
  int r0 = ch * 16 + w * 4;  // first row of this wave
  const float* wtb = &wt[(size_t)b * 16384];
  const float* xrow = &x[(size_t)b * 1024];
  const float* memb = &mem[(size_t)b * (size_t)MM * 1024];

  const float* rp[4];
#pragma unroll
  for (int r = 0; r < 4; ++r) {
    int l = min(r0 + r, LL - 1);
    rp[r] = (l < MM) ? (memb + (size_t)l * 1024) : xrow;
  }

  float p[16];  // flattened [r*4 + jh]
#pragma unroll
  for (int i = 0; i < 16; ++i) p[i] = 0.f;

  int co = cg * 4;
#pragma unroll
  for (int q = 0; q < 4; ++q) {
    float4 wr[4][4];
#pragma unroll
    for (int j = 0; j < 4; ++j)
#pragma unroll
      for (int jh = 0; jh < 4; ++jh)
        wr[j][jh] = *(const float4*)&wtb[(hl + 4 * jh) * 1024 +
                                         (4 * q + j) * 64 + co];
#pragma unroll
    for (int r = 0; r < 4; ++r) {
      float4 cv[4];
#pragma unroll
      for (int j = 0; j < 4; ++j)
        cv[j] = *(const float4*)&rp[r][(4 * q + j) * 64 + co];
#pragma unroll
      for (int j = 0; j < 4; ++j) {
#pragma unroll
        for (int jh = 0; jh < 4; ++jh) {
          p[r * 4 + jh] += cv[j].x * wr[j][jh].x + cv[j].y * wr[j][jh].y +
                           cv[j].z * wr[j][jh].z + cv[j].w * wr[j][jh].w;
        }
      }
    }
  }

  // packed butterfly over cg bits (masks 1,2,4,8): 16 values -> 1 per lane.
  // After step s with mask m: kept array element i corresponds to original
  // flattened index accumulating (lane bit s) * (n/2).
#pragma unroll
  for (int s = 0; s < 4; ++s) {
    int m = 1 << s;
    int half = (16 >> s) >> 1;
    bool up = (lane & m) != 0;
#pragma unroll
    for (int i = 0; i < 8; ++i) {
      if (i < half) {
        float send = up ? p[i] : p[i + half];
        float keep = up ? p[i + half] : p[i];
        p[i] = keep + __shfl_xor(send, m, 64);
      }
    }
  }
  // lane holds flattened idx = bitrev4(cg)
  int idx = ((cg & 1) << 3) | ((cg & 2) << 1) | ((cg & 4) >> 1) | ((cg & 8) >> 3);
  int r = idx >> 2, jh = idx & 3;
  int h = hl + 4 * jh;
  int row = r0 + r;
  if (row < LL)
    logits[(size_t)(b * 16 + h) * LL + row] = p[0];
}

// ---------------- softmax over l: reads (ac + bd)*scale, writes attn in place ----
__global__ __launch_bounds__(256) void k_softmax(float* __restrict__ logits,
                                                 const float* __restrict__ bd) {
  __shared__ float red[8];
  int t = threadIdx.x;
  size_t base = (size_t)blockIdx.x * LL;
  float rv[9];
  float m = -1e30f;
#pragma unroll
  for (int k = 0; k < 9; ++k) {
    int i = t + k * 256;
    rv[k] = (i < LL) ? (logits[base + i] + bd[base + i]) * SCALE : -1e30f;
    m = fmaxf(m, rv[k]);
  }
#pragma unroll
  for (int s = 1; s < 64; s <<= 1) m = fmaxf(m, __shfl_xor(m, s, 64));
  if ((t & 63) == 0) red[t >> 6] = m;
  __syncthreads();
  m = fmaxf(fmaxf(red[0], red[1]), fmaxf(red[2], red[3]));
  float sum = 0.f;
#pragma unroll
  for (int k = 0; k < 9; ++k) {
    int i = t + k * 256;
    float e = __expf(rv[k] - m);
    rv[k] = e;
    if (i < LL) sum += e;
  }
#pragma unroll
  for (int s = 1; s < 64; s <<= 1) sum += __shfl_xor(sum, s, 64);
  if ((t & 63) == 0) red[4 + (t >> 6)] = sum;
  __syncthreads();
  float inv = 1.0f / (red[4] + red[5] + red[6] + red[7]);
#pragma unroll
  for (int k = 0; k < 9; ++k) {
    int i = t + k * 256;
    if (i < LL) logits[base + i] = rv[k] * inv;
  }
}

// ---------------- ctx pass: register-resident, global-direct ----------------
__global__ __launch_bounds__(256) void k_ctx(
    const float* __restrict__ x, const float* __restrict__ mem,
    const float* __restrict__ attn, float* __restrict__ part) {
  __shared__ __attribute__((aligned(16))) float att_s[CHC * 20];
  int t = threadIdx.x;
  int lane = t & 63, w = t >> 6;
  int b = blockIdx.y;
  int ch = blockIdx.x >> 2, cq = blockIdx.x & 3;
  int l0 = ch * CHC, lend = min(LL, l0 + CHC);
  int natt = lend - l0;
  int c_off = cq * 256 + lane * 4;
#pragma unroll
  for (int h = 0; h < 16; ++h)
    for (int r = t; r < natt; r += 256)
      att_s[r * 20 + h] = attn[(size_t)(b * 16 + h) * LL + l0 + r];
  __syncthreads();
  float4 acc[16];
#pragma unroll
  for (int i = 0; i < 16; ++i) acc[i] = make_float4(0.f, 0.f, 0.f, 0.f);
  const float* xrow = &x[(size_t)b * 1024 + c_off];
  const float* memb = &mem[(size_t)b * MM * 1024 + c_off];

  for (int g0 = l0 + w * 8; g0 < lend; g0 += 32) {
    int nr = min(8, lend - g0);
    float4 rb[8];
#pragma unroll
    for (int r = 0; r < 8; ++r) {
      int l = g0 + r;
      rb[r] = *(const float4*)((l < MM) ? &memb[(size_t)l * 1024] : xrow);
    }
#pragma unroll
    for (int r = 0; r < 8; ++r) {
      if (r < nr) {
        int ri = g0 + r - l0;
        const float4* a4 = (const float4*)&att_s[ri * 20];
        float4 aA = a4[0], aB = a4[1], aC = a4[2], aD = a4[3];
        float4 rv = rb[r];
#define ACC1(i, s)                                                       \
  acc[i].x += (s) * rv.x; acc[i].y += (s) * rv.y;                        \
  acc[i].z += (s) * rv.z; acc[i].w += (s) * rv.w;
        ACC1(0, aA.x) ACC1(1, aA.y) ACC1(2, aA.z) ACC1(3, aA.w)
        ACC1(4, aB.x) ACC1(5, aB.y) ACC1(6, aB.z) ACC1(7, aB.w)
        ACC1(8, aC.x) ACC1(9, aC.y) ACC1(10, aC.z) ACC1(11, aC.w)
        ACC1(12, aD.x) ACC1(13, aD.y) ACC1(14, aD.z) ACC1(15, aD.w)
#undef ACC1
      }
    }
  }
  __syncthreads();
  float* accb = att_s;
  for (int ww = 0; ww < 4; ++ww) {
    if (w == ww) {
      if (ww == 0) {
#pragma unroll
        for (int h = 0; h < 16; ++h)
          *(float4*)&accb[h * 256 + lane * 4] = acc[h];
      } else {
#pragma unroll
        for (int h = 0; h < 16; ++h) {
          float4 vv = *(const float4*)&accb[h * 256 + lane * 4];
          vv.x += acc[h].x; vv.y += acc[h].y;
          vv.z += acc[h].z; vv.w += acc[h].w;
          *(float4*)&accb[h * 256 + lane * 4] = vv;
        }
      }
    }
    __syncthreads();
  }
  size_t pb = (size_t)((b * NCHC + ch) * 16) * 1024 + cq * 256;
  for (int idx = t; idx < 1024; idx += 256) {
    int h = idx >> 6, c4 = idx & 63;
    *(float4*)&part[pb + (size_t)h * 1024 + 4 * c4] =
        *(const float4*)&accb[h * 256 + 4 * c4];
  }
}

// ---------------- sum 9 chunk partials -> ctx ----------------
__global__ __launch_bounds__(256) void k_ctxreduce(
    const float* __restrict__ part, float* __restrict__ ctx) {
  int o4 = blockIdx.x * 256 + threadIdx.x;
  size_t o = (size_t)o4 * 4;
  int b = (int)(o >> 14);
  int rem = (int)(o & 16383);
  const float* p = &part[(size_t)b * (NCHC * 16384) + rem];
  float4 s = *(const float4*)p;
#pragma unroll
  for (int chk = 1; chk < NCHC; ++chk) {
    float4 v = *(const float4*)&p[(size_t)chk * 16384];
    s.x += v.x; s.y += v.y; s.z += v.z; s.w += v.w;
  }
  *(float4*)&ctx[o] = s;
}

extern "C" void kernel_launch(void* const* d_in, const int* in_sizes, int n_in,
                              void* d_out, int out_size, void* d_ws,
                              size_t ws_size, hipStream_t stream) {
  const float* x = (const float*)d_in[0];
  const float* mem = (const float*)d_in[1];
  const float* Wq = (const float*)d_in[2];
  const float* bq = (const float*)d_in[3];
  const float* Wk = (const float*)d_in[4];
  // d_in[5] = bk : constant over l -> cancels in softmax, unused.
  const float* Wv = (const float*)d_in[6];
  const float* bv = (const float*)d_in[7];
  const float* u_bias = (const float*)d_in[8];
  const float* v_bias = (const float*)d_in[9];
  const float* Wo = (const float*)d_in[10];
  const float* bo = (const float*)d_in[11];
  float* out = (float*)d_out;

  float* ws = (float*)d_ws;
  // Region A (persistent): 3,343,360 floats
  float* qu = ws;                         // 65536
  float* qv = qu + 65536;                 // 65536
  float* logits = qv + 65536;             // 2098176
  float* ctx = logits + 2098176;          // 1048576
  float* out1 = ctx + 1048576;            // 65536
  // Region B (aliased): 9,437,184 floats (= part)
  float* Bb = out1 + 65536;
  float* P = Bb;                          // 524288
  float* wt = Bb + 524288;                // 1048576 (dead after k_logits7)
  float* rtab = Bb + 524288 + 1048576;    // 131200  (dead after k_bd)
  float* bd = Bb + 524288 + 1048576 + 131200;  // 2098176 (dead after k_softmax)
  float* part = Bb;                       // 9437184 (k_ctx..k_ctxreduce only)
  // total = 12,780,544 floats = 51.1 MB

  k_gemm<<<dim3(16, 8), 256, 0, stream>>>(x, 1024, 0, Wq, P);
  k_rtab<<<dim3(513), 256, 0, stream>>>(rtab);
  k_reduce_qp<<<dim3(64), 256, 0, stream>>>(P, bq, u_bias, v_bias, qu, qv);
  k_wtilde<<<dim3(16, 16), 256, 0, stream>>>(qu, Wk, wt);
  k_bd<<<dim3(17, 64), 256, 0, stream>>>(qv, rtab, bd);
  k_logits7<<<dim3(129, 64), 256, 0, stream>>>(x, mem, wt, logits);
  k_softmax<<<dim3(1024), 256, 0, stream>>>(logits, bd);
  k_ctx<<<dim3(36, 64), 256, 0, stream>>>(x, mem, logits, part);
  k_ctxreduce<<<dim3(1024), 256, 0, stream>>>(part, ctx);
  k_gemm<<<dim3(16, 8), 256, 0, stream>>>(ctx, 16384, 1024, Wv, P);
  k_reduce1<<<dim3(64), 256, 0, stream>>>(P, bv, out1);
  k_gemm<<<dim3(16, 8), 256, 0, stream>>>(out1, 1024, 0, Wo, P);
  k_reduce1<<<dim3(64), 256, 0, stream>>>(P, bo, out);
}

// Round 9
// 401.760 us; speedup vs baseline: 6.3624x; 1.6356x over previous
//
#include <hip/hip_runtime.h>
#include <hip/hip_bf16.h>
#include <math.h>

// Problem constants
#define B   64
#define C   1024
#define HH  16
#define DD  64
#define MM  2048
#define LL  2049   // M+1
#define SCALE 0.125f
#define NCHC 9     // ctx row chunks
#define CHC  228   // rows per ctx chunk (9*228 = 2052 >= 2049)

// DPP helper: keep + quad_perm<CTRL>(send). CTRL 0xB1 = xor1, 0x4E = xor2.
template <int CTRL>
__device__ __forceinline__ float dpp_add(float keep, float send) {
  int moved =
      __builtin_amdgcn_update_dpp(0, __float_as_int(send), CTRL, 0xF, 0xF, true);
  return keep + __int_as_float(moved);
}

// ---------------- generic split-K GEMM: out_partial[kc][64][1024] ----------------
__global__ __launch_bounds__(256) void k_gemm(
    const float* __restrict__ A, int a_row_stride, int a_bx_off,
    const float* __restrict__ W, float* __restrict__ P) {
  __shared__ __attribute__((aligned(16))) float a_s[64 * 132];
  __shared__ __attribute__((aligned(16))) float b_s[128 * 68];
  int t = threadIdx.x;
  int jt = blockIdx.x, kc = blockIdx.y;
  const float* Ab = A + (size_t)jt * a_bx_off;
  int k0 = kc * 128;
  for (int idx = t; idx < 2048; idx += 256) {
    int bb = idx >> 5, f4 = idx & 31;
    float4 v = *(const float4*)&Ab[(size_t)bb * a_row_stride + k0 + 4 * f4];
    *(float4*)&a_s[bb * 132 + 4 * f4] = v;
  }
  for (int idx = t; idx < 2048; idx += 256) {
    int kk = idx >> 4, f4 = idx & 15;
    float4 v = *(const float4*)&W[(size_t)(k0 + kk) * 1024 + jt * 64 + 4 * f4];
    *(float4*)&b_s[kk * 68 + 4 * f4] = v;
  }
  __syncthreads();
  int j0 = (t & 15) * 4, b0 = (t >> 4) * 4;
  float4 acc[4];
#pragma unroll
  for (int i = 0; i < 4; ++i) acc[i] = make_float4(0.f, 0.f, 0.f, 0.f);
  for (int k = 0; k < 128; k += 4) {
    float4 w0 = *(const float4*)&b_s[(k + 0) * 68 + j0];
    float4 w1 = *(const float4*)&b_s[(k + 1) * 68 + j0];
    float4 w2 = *(const float4*)&b_s[(k + 2) * 68 + j0];
    float4 w3 = *(const float4*)&b_s[(k + 3) * 68 + j0];
#pragma unroll
    for (int i = 0; i < 4; ++i) {
      float4 av = *(const float4*)&a_s[(b0 + i) * 132 + k];
      acc[i].x += av.x * w0.x + av.y * w1.x + av.z * w2.x + av.w * w3.x;
      acc[i].y += av.x * w0.y + av.y * w1.y + av.z * w2.y + av.w * w3.y;
      acc[i].z += av.x * w0.z + av.y * w1.z + av.z * w2.z + av.w * w3.z;
      acc[i].w += av.x * w0.w + av.y * w1.w + av.z * w2.w + av.w * w3.w;
    }
  }
  size_t ob = (size_t)kc * 65536 + jt * 64;
#pragma unroll
  for (int i = 0; i < 4; ++i)
    *(float4*)&P[ob + (size_t)(b0 + i) * 1024 + j0] = acc[i];
}

__global__ __launch_bounds__(256) void k_reduce_qp(
    const float* __restrict__ P, const float* __restrict__ bq,
    const float* __restrict__ u, const float* __restrict__ v,
    float* __restrict__ qu, float* __restrict__ qv) {
  int idx = blockIdx.x * 256 + threadIdx.x;
  int b = idx >> 8, f4 = idx & 255;
  size_t off = (size_t)b * 1024 + 4 * f4;
  float4 s = *(const float4*)&P[off];
#pragma unroll
  for (int kc = 1; kc < 8; ++kc) {
    float4 t4 = *(const float4*)&P[(size_t)kc * 65536 + off];
    s.x += t4.x; s.y += t4.y; s.z += t4.z; s.w += t4.w;
  }
  float4 bb = *(const float4*)&bq[4 * f4];
  s.x += bb.x; s.y += bb.y; s.z += bb.z; s.w += bb.w;
  float4 uu = *(const float4*)&u[4 * f4];
  float4 vv = *(const float4*)&v[4 * f4];
  float4 o1 = make_float4(s.x + uu.x, s.y + uu.y, s.z + uu.z, s.w + uu.w);
  float4 o2 = make_float4(s.x + vv.x, s.y + vv.y, s.z + vv.z, s.w + vv.w);
  *(float4*)&qu[off] = o1;
  *(float4*)&qv[off] = o2;
}

__global__ __launch_bounds__(256) void k_reduce1(
    const float* __restrict__ P, const float* __restrict__ bias,
    float* __restrict__ out) {
  int idx = blockIdx.x * 256 + threadIdx.x;
  int b = idx >> 8, f4 = idx & 255;
  size_t off = (size_t)b * 1024 + 4 * f4;
  float4 s = *(const float4*)&P[off];
#pragma unroll
  for (int kc = 1; kc < 8; ++kc) {
    float4 t4 = *(const float4*)&P[(size_t)kc * 65536 + off];
    s.x += t4.x; s.y += t4.y; s.z += t4.z; s.w += t4.w;
  }
  float4 bb = *(const float4*)&bias[4 * f4];
  s.x += bb.x; s.y += bb.y; s.z += bb.z; s.w += bb.w;
  *(float4*)&out[off] = s;
}

// ---------------- wtilde: per-h GEMM ----------------
__global__ __launch_bounds__(256) void k_wtilde(
    const float* __restrict__ qu, const float* __restrict__ Wk,
    float* __restrict__ wt) {
  __shared__ __attribute__((aligned(16))) float a_s[64 * 68];
  __shared__ __attribute__((aligned(16))) float w_s[64 * 68];
  int t = threadIdx.x, ct = blockIdx.x, h = blockIdx.y;
  for (int idx = t; idx < 1024; idx += 256) {
    int bb = idx >> 4, f4 = idx & 15;
    *(float4*)&a_s[bb * 68 + 4 * f4] =
        *(const float4*)&qu[(size_t)bb * 1024 + h * 64 + 4 * f4];
  }
  for (int idx = t; idx < 1024; idx += 256) {
    int cc = idx >> 4, f4 = idx & 15;
    *(float4*)&w_s[cc * 68 + 4 * f4] =
        *(const float4*)&Wk[(size_t)(ct * 64 + cc) * 1024 + h * 64 + 4 * f4];
  }
  __syncthreads();
  int c0 = (t & 15) * 4, b0 = (t >> 4) * 4;
  float acc[4][4] = {};
  for (int d = 0; d < 64; d += 4) {
    float4 w0 = *(const float4*)&w_s[(c0 + 0) * 68 + d];
    float4 w1 = *(const float4*)&w_s[(c0 + 1) * 68 + d];
    float4 w2 = *(const float4*)&w_s[(c0 + 2) * 68 + d];
    float4 w3 = *(const float4*)&w_s[(c0 + 3) * 68 + d];
#pragma unroll
    for (int i = 0; i < 4; ++i) {
      float4 av = *(const float4*)&a_s[(b0 + i) * 68 + d];
      acc[i][0] += av.x * w0.x + av.y * w0.y + av.z * w0.z + av.w * w0.w;
      acc[i][1] += av.x * w1.x + av.y * w1.y + av.z * w1.z + av.w * w1.w;
      acc[i][2] += av.x * w2.x + av.y * w2.y + av.z * w2.z + av.w * w2.w;
      acc[i][3] += av.x * w3.x + av.y * w3.y + av.z * w3.z + av.w * w3.w;
    }
  }
#pragma unroll
  for (int i = 0; i < 4; ++i) {
    float4 o = make_float4(acc[i][0], acc[i][1], acc[i][2], acc[i][3]);
    *(float4*)&wt[(size_t)((b0 + i) * 16 + h) * 1024 + ct * 64 + c0] = o;
  }
}

// ---------------- sinusoidal table, reversed ----------------
__global__ void k_rtab(float* __restrict__ rtab) {
  int idx = blockIdx.x * 256 + threadIdx.x;
  if (idx >= LL * 64) return;
  int l = idx >> 6, d = idx & 63;
  float p = (float)(LL - 1 - l);
  int dd = d & 31;
  float f = 1.0f / powf(10000.0f, (float)dd * (1.0f / 32.0f));
  float a = p * f;
  rtab[idx] = (d < 32) ? sinf(a) : cosf(a);
}

// ---------------- bd[b,h,l] = sum_d qv[b,h,d]*rtab[l,d] ----------------
// grid (17, 64): 128 l-rows per block
__global__ __launch_bounds__(256) void k_bd(
    const float* __restrict__ qv, const float* __restrict__ rtab,
    float* __restrict__ bd) {
  __shared__ __attribute__((aligned(16))) float rt_s[128 * 68];
  int t = threadIdx.x, ch = blockIdx.x, b = blockIdx.y;
  int l0 = ch * 128;
  int nrows = min(128, LL - l0);
  for (int idx = t; idx < nrows * 16; idx += 256) {
    int r = idx >> 4, d4 = idx & 15;
    *(float4*)&rt_s[r * 68 + 4 * d4] =
        *(const float4*)&rtab[(size_t)(l0 + r) * 64 + 4 * d4];
  }
  __syncthreads();
  for (int idx = t; idx < 16 * 128; idx += 256) {
    int h = idx >> 7, r = idx & 127;
    if (r < nrows) {
      const float* qh = &qv[(size_t)b * 1024 + h * 64];
      const float* rr = &rt_s[r * 68];
      float s = 0.f;
#pragma unroll
      for (int d4 = 0; d4 < 16; ++d4) {
        float4 rv = *(const float4*)&rr[4 * d4];
        float4 qq = *(const float4*)&qh[4 * d4];
        s += rv.x * qq.x + rv.y * qq.y + rv.z * qq.z + rv.w * qq.w;
      }
      bd[(size_t)(b * 16 + h) * LL + l0 + r] = s;
    }
  }
}

// ---------------- logits pass: register-resident, global-direct ----------------
// grid (17, 64): 128 rows per block; 4 waves c-split (256 c each);
// lane owns 4 c with wt for all 16 h in registers. Butterfly reduce with
// bits 0,1 via exact DPP quad_perm (VALU pipe) and bits 2..5 via shfl_xor:
// 6 DS ops per row per wave instead of 18 (round-3 version).
__global__ __launch_bounds__(256) void k_logits(
    const float* __restrict__ x, const float* __restrict__ mem,
    const float* __restrict__ wt, const float* __restrict__ bd,
    float* __restrict__ logits) {
  __shared__ float red_s[8 * 68];
  int t = threadIdx.x;
  int lane = t & 63, w = t >> 6;
  int b = blockIdx.y, ch = blockIdx.x;
  int l0 = ch * 128, lend = min(LL, l0 + 128);
  int c_off = w * 256 + lane * 4;
  float4 wr[16];
#pragma unroll
  for (int h = 0; h < 16; ++h)
    wr[h] = *(const float4*)&wt[(size_t)(b * 16 + h) * 1024 + c_off];
  const float* xrow = &x[(size_t)b * 1024 + c_off];
  const float* memb = &mem[(size_t)b * MM * 1024 + c_off];
  bool u0 = (lane & 1) != 0, u1 = (lane & 2) != 0;
  bool u2 = (lane & 4) != 0, u3 = (lane & 8) != 0;
  // after consuming bits 0..3: lane holds h = 8*b0 + 4*b1 + 2*b2 + b3
  int hmap = ((lane & 1) << 3) | ((lane & 2) << 1) | ((lane & 4) >> 1) |
             ((lane & 8) >> 3);

  for (int g0 = l0; g0 < lend; g0 += 8) {
    int nr = min(8, lend - g0);
    float4 rb[8];
#pragma unroll
    for (int r = 0; r < 8; ++r) {
      int l = g0 + r;
      rb[r] = *(const float4*)((l < MM) ? &memb[(size_t)l * 1024] : xrow);
    }
#pragma unroll
    for (int r = 0; r < 8; ++r) {
      if (r < nr) {
        float4 rv = rb[r];
        float p[16];
#pragma unroll
        for (int h = 0; h < 16; ++h)
          p[h] = rv.x * wr[h].x + rv.y * wr[h].y + rv.z * wr[h].z +
                 rv.w * wr[h].w;
        // packed butterfly, bits low->high. masks 1,2: DPP quad_perm (VALU).
#pragma unroll
        for (int i = 0; i < 8; ++i) {
          float send = u0 ? p[i] : p[i + 8];
          float keep = u0 ? p[i + 8] : p[i];
          p[i] = dpp_add<0xB1>(keep, send);
        }
#pragma unroll
        for (int i = 0; i < 4; ++i) {
          float send = u1 ? p[i] : p[i + 4];
          float keep = u1 ? p[i + 4] : p[i];
          p[i] = dpp_add<0x4E>(keep, send);
        }
#pragma unroll
        for (int i = 0; i < 2; ++i) {
          float send = u2 ? p[i] : p[i + 2];
          float keep = u2 ? p[i + 2] : p[i];
          p[i] = keep + __shfl_xor(send, 4, 64);
        }
        {
          float send = u3 ? p[0] : p[1];
          float keep = u3 ? p[1] : p[0];
          float u = keep + __shfl_xor(send, 8, 64);
          u += __shfl_xor(u, 16, 64);
          u += __shfl_xor(u, 32, 64);
          if (lane < 16) red_s[r * 68 + w * 16 + hmap] = u;
        }
      }
    }
    __syncthreads();
    if (t < 128) {
      int r8 = t & 7, h = t >> 3;
      if (r8 < nr) {
        float s = red_s[r8 * 68 + h] + red_s[r8 * 68 + 16 + h] +
                  red_s[r8 * 68 + 32 + h] + red_s[r8 * 68 + 48 + h];
        int l = g0 + r8;
        size_t o = (size_t)(b * 16 + h) * LL + l;
        logits[o] = (s + bd[o]) * SCALE;
      }
    }
    __syncthreads();
  }
}

// ---------------- softmax over l, in place. grid 1024 (b*16+h) ----------------
__global__ __launch_bounds__(256) void k_softmax(float* __restrict__ logits) {
  __shared__ float red[8];
  int t = threadIdx.x;
  size_t base = (size_t)blockIdx.x * LL;
  float rv[9];
  float m = -1e30f;
#pragma unroll
  for (int k = 0; k < 9; ++k) {
    int i = t + k * 256;
    rv[k] = (i < LL) ? logits[base + i] : -1e30f;
    m = fmaxf(m, rv[k]);
  }
#pragma unroll
  for (int s = 1; s < 64; s <<= 1) m = fmaxf(m, __shfl_xor(m, s, 64));
  if ((t & 63) == 0) red[t >> 6] = m;
  __syncthreads();
  m = fmaxf(fmaxf(red[0], red[1]), fmaxf(red[2], red[3]));
  float sum = 0.f;
#pragma unroll
  for (int k = 0; k < 9; ++k) {
    int i = t + k * 256;
    float e = __expf(rv[k] - m);
    rv[k] = e;
    if (i < LL) sum += e;
  }
#pragma unroll
  for (int s = 1; s < 64; s <<= 1) sum += __shfl_xor(sum, s, 64);
  if ((t & 63) == 0) red[4 + (t >> 6)] = sum;
  __syncthreads();
  float inv = 1.0f / (red[4] + red[5] + red[6] + red[7]);
#pragma unroll
  for (int k = 0; k < 9; ++k) {
    int i = t + k * 256;
    if (i < LL) logits[base + i] = rv[k] * inv;
  }
}

// ---------------- ctx pass: register-resident, global-direct ----------------
// grid (36, 64): bx = ch*4 + cq. Block: rows [ch*228, +228), c-quarter cq.
// 4 waves split rows (8-row groups, stride 32); lane owns 4 c, acc[16h].
__global__ __launch_bounds__(256) void k_ctx(
    const float* __restrict__ x, const float* __restrict__ mem,
    const float* __restrict__ attn, float* __restrict__ part) {
  __shared__ __attribute__((aligned(16))) float att_s[CHC * 20];
  int t = threadIdx.x;
  int lane = t & 63, w = t >> 6;
  int b = blockIdx.y;
  int ch = blockIdx.x >> 2, cq = blockIdx.x & 3;
  int l0 = ch * CHC, lend = min(LL, l0 + CHC);
  int natt = lend - l0;
  int c_off = cq * 256 + lane * 4;
#pragma unroll
  for (int h = 0; h < 16; ++h)
    for (int r = t; r < natt; r += 256)
      att_s[r * 20 + h] = attn[(size_t)(b * 16 + h) * LL + l0 + r];
  __syncthreads();
  float4 acc[16];
#pragma unroll
  for (int i = 0; i < 16; ++i) acc[i] = make_float4(0.f, 0.f, 0.f, 0.f);
  const float* xrow = &x[(size_t)b * 1024 + c_off];
  const float* memb = &mem[(size_t)b * MM * 1024 + c_off];

  for (int g0 = l0 + w * 8; g0 < lend; g0 += 32) {
    int nr = min(8, lend - g0);
    float4 rb[8];
#pragma unroll
    for (int r = 0; r < 8; ++r) {
      int l = g0 + r;
      rb[r] = *(const float4*)((l < MM) ? &memb[(size_t)l * 1024] : xrow);
    }
#pragma unroll
    for (int r = 0; r < 8; ++r) {
      if (r < nr) {
        int ri = g0 + r - l0;
        const float4* a4 = (const float4*)&att_s[ri * 20];
        float4 aA = a4[0], aB = a4[1], aC = a4[2], aD = a4[3];
        float4 rv = rb[r];
#define ACC1(i, s)                                                       \
  acc[i].x += (s) * rv.x; acc[i].y += (s) * rv.y;                        \
  acc[i].z += (s) * rv.z; acc[i].w += (s) * rv.w;
        ACC1(0, aA.x) ACC1(1, aA.y) ACC1(2, aA.z) ACC1(3, aA.w)
        ACC1(4, aB.x) ACC1(5, aB.y) ACC1(6, aB.z) ACC1(7, aB.w)
        ACC1(8, aC.x) ACC1(9, aC.y) ACC1(10, aC.z) ACC1(11, aC.w)
        ACC1(12, aD.x) ACC1(13, aD.y) ACC1(14, aD.z) ACC1(15, aD.w)
#undef ACC1
      }
    }
  }
  // cross-wave merge in LDS (reuse att_s: 4096 <= 4560 floats)
  __syncthreads();
  float* accb = att_s;
  for (int ww = 0; ww < 4; ++ww) {
    if (w == ww) {
      if (ww == 0) {
#pragma unroll
        for (int h = 0; h < 16; ++h)
          *(float4*)&accb[h * 256 + lane * 4] = acc[h];
      } else {
#pragma unroll
        for (int h = 0; h < 16; ++h) {
          float4 vv = *(const float4*)&accb[h * 256 + lane * 4];
          vv.x += acc[h].x; vv.y += acc[h].y;
          vv.z += acc[h].z; vv.w += acc[h].w;
          *(float4*)&accb[h * 256 + lane * 4] = vv;
        }
      }
    }
    __syncthreads();
  }
  size_t pb = (size_t)((b * NCHC + ch) * 16) * 1024 + cq * 256;
  for (int idx = t; idx < 1024; idx += 256) {
    int h = idx >> 6, c4 = idx & 63;
    *(float4*)&part[pb + (size_t)h * 1024 + 4 * c4] =
        *(const float4*)&accb[h * 256 + 4 * c4];
  }
}

// ---------------- sum 9 chunk partials -> ctx ----------------
__global__ __launch_bounds__(256) void k_ctxreduce(
    const float* __restrict__ part, float* __restrict__ ctx) {
  int o4 = blockIdx.x * 256 + threadIdx.x;
  size_t o = (size_t)o4 * 4;
  int b = (int)(o >> 14);
  int rem = (int)(o & 16383);
  const float* p = &part[(size_t)b * (NCHC * 16384) + rem];
  float4 s = *(const float4*)p;
#pragma unroll
  for (int chk = 1; chk < NCHC; ++chk) {
    float4 v = *(const float4*)&p[(size_t)chk * 16384];
    s.x += v.x; s.y += v.y; s.z += v.z; s.w += v.w;
  }
  *(float4*)&ctx[o] = s;
}

extern "C" void kernel_launch(void* const* d_in, const int* in_sizes, int n_in,
                              void* d_out, int out_size, void* d_ws,
                              size_t ws_size, hipStream_t stream) {
  const float* x = (const float*)d_in[0];
  const float* mem = (const float*)d_in[1];
  const float* Wq = (const float*)d_in[2];
  const float* bq = (const float*)d_in[3];
  const float* Wk = (const float*)d_in[4];
  // d_in[5] = bk : constant over l -> cancels in softmax, unused.
  const float* Wv = (const float*)d_in[6];
  const float* bv = (const float*)d_in[7];
  const float* u_bias = (const float*)d_in[8];
  const float* v_bias = (const float*)d_in[9];
  const float* Wo = (const float*)d_in[10];
  const float* bo = (const float*)d_in[11];
  float* out = (float*)d_out;

  float* ws = (float*)d_ws;
  // Region A (persistent): 3,343,360 floats
  float* qu = ws;                         // 65536
  float* qv = qu + 65536;                 // 65536
  float* logits = qv + 65536;             // 2098176
  float* ctx = logits + 2098176;          // 1048576
  float* out1 = ctx + 1048576;            // 65536
  // Region B (aliased): 9,437,184 floats (= part)
  float* Bb = out1 + 65536;
  float* wt = Bb;                         // 1048576 (dead after k_logits)
  float* rtab = Bb + 1048576;             // 131200  (dead after k_bd)
  float* bd = Bb + 1179776;               // 2098176 (dead after k_logits)
  float* P = Bb + 3277952;                // 524288  (early use + post-part use)
  float* part = Bb;                       // 9437184 (k_ctx..k_ctxreduce only)
  // total = 12,780,544 floats = 51.1 MB

  k_gemm<<<dim3(16, 8), 256, 0, stream>>>(x, 1024, 0, Wq, P);
  k_rtab<<<dim3(513), 256, 0, stream>>>(rtab);
  k_reduce_qp<<<dim3(64), 256, 0, stream>>>(P, bq, u_bias, v_bias, qu, qv);
  k_wtilde<<<dim3(16, 16), 256, 0, stream>>>(qu, Wk, wt);
  k_bd<<<dim3(17, 64), 256, 0, stream>>>(qv, rtab, bd);
  k_logits<<<dim3(17, 64), 256, 0, stream>>>(x, mem, wt, bd, logits);
  k_softmax<<<dim3(1024), 256, 0, stream>>>(logits);
  k_ctx<<<dim3(36, 64), 256, 0, stream>>>(x, mem, logits, part);
  k_ctxreduce<<<dim3(1024), 256, 0, stream>>>(part, ctx);
  k_gemm<<<dim3(16, 8), 256, 0, stream>>>(ctx, 16384, 1024, Wv, P);
  k_reduce1<<<dim3(64), 256, 0, stream>>>(P, bv, out1);
  k_gemm<<<dim3(16, 8), 256, 0, stream>>>(out1, 1024, 0, Wo, P);
  k_reduce1<<<dim3(64), 256, 0, stream>>>(P, bo, out);
}